// Round 2
// baseline (818.296 us; speedup 1.0000x reference)
//
#include <hip/hip_runtime.h>
#include <math.h>

#define PI_F 3.14159265358979323846f
#define REP 8   // DIAGNOSTIC: repeat each (idempotent) kernel body 8x so our
                // kernels surface in the rocprof top-5 and so
                // (dur[REP=8]-dur[REP=1])/7 yields true kernel time.

// Shapes: B=4, X=Y=Z=64, CIN=COUT=32, modes 16.  Baseline (288us) structure.

// ---------------- K1: forward z-DFT ----------------------------------------
// grid 1024 = (b4, x16, yg8, ih2); block 256; tile 2kz x 4i per thread.
__global__ __launch_bounds__(256) void k_dft_z(const float* __restrict__ x,
                                               float2* __restrict__ T1) {
    int bid = blockIdx.x;
    int ih = bid & 1, yg = (bid >> 1) & 7, xx = (bid >> 4) & 15, b = bid >> 8;
    __shared__ float  sx[8192];      // [y8][z64][i16] 32KB
    __shared__ float2 twt[1024];     // [z][kz16] 8KB
    #pragma unroll 1
    for (int rep = 0; rep < REP; ++rep) {
        float4* sx4 = (float4*)sx;
        const float4* src4 = (const float4*)(x + (size_t)((b * 64 + xx) * 64 + yg * 8) * 2048) + ih * 4;
        #pragma unroll
        for (int t = threadIdx.x; t < 2048; t += 256) {
            int i4 = t & 3, z = (t >> 2) & 63, y = t >> 8;
            sx4[(y * 64 + z) * 4 + i4] = src4[(size_t)y * 512 + z * 8 + i4];
        }
        const float cn = -2.0f * PI_F / 64.0f;
        for (int t = threadIdx.x; t < 1024; t += 256) {
            int z = t >> 4, kz = t & 15;
            float s, c; sincosf(cn * (float)((z * kz) & 63), &s, &c);
            twt[t] = make_float2(c, s);
        }
        __syncthreads();
        int ig = threadIdx.x & 3, kz2 = (threadIdx.x >> 2) & 7, y8 = threadIdx.x >> 5;
        float ar0[4], ai0[4], ar1[4], ai1[4];
        #pragma unroll
        for (int j = 0; j < 4; j++) { ar0[j] = ai0[j] = ar1[j] = ai1[j] = 0.f; }
        const float4* twv = (const float4*)twt;   // [z][8]: (c0,s0,c1,s1) per kz-pair
        #pragma unroll 8
        for (int z = 0; z < 64; z++) {
            float4 va = sx4[(y8 * 64 + z) * 4 + ig];
            float4 tp = twv[z * 8 + kz2];
            float v[4] = {va.x, va.y, va.z, va.w};
            #pragma unroll
            for (int j = 0; j < 4; j++) {
                ar0[j] = fmaf(v[j], tp.x, ar0[j]);
                ai0[j] = fmaf(v[j], tp.y, ai0[j]);
                ar1[j] = fmaf(v[j], tp.z, ar1[j]);
                ai1[j] = fmaf(v[j], tp.w, ai1[j]);
            }
        }
        int y = yg * 8 + y8, kz0 = kz2 * 2, i0 = ih * 16 + ig * 4;
        float2* dst = T1 + (size_t)((b * 16 + xx) * 64 + y) * 512;
        float4* d0 = (float4*)(dst + kz0 * 32 + i0);
        d0[0] = make_float4(ar0[0], ai0[0], ar0[1], ai0[1]);
        d0[1] = make_float4(ar0[2], ai0[2], ar0[3], ai0[3]);
        float4* d1 = (float4*)(dst + (kz0 + 1) * 32 + i0);
        d1[0] = make_float4(ar1[0], ai1[0], ar1[1], ai1[1]);
        d1[1] = make_float4(ar1[2], ai1[2], ar1[3], ai1[3]);
        __syncthreads();
        asm volatile("" ::: "memory");
    }
}

// ---------------- K2: forward y-DFT ----------------------------------------
// grid 512 = (b4, x16, kzg4, ih2); block 256; tile 2ky x 2i per thread.
__global__ __launch_bounds__(256) void k_dft_y(const float2* __restrict__ T1,
                                               float2* __restrict__ XH) {
    int bid = blockIdx.x;
    int ih = bid & 1, kzg = (bid >> 1) & 3, xx = (bid >> 3) & 15, b = bid >> 7;
    __shared__ float4 sT4[2304];     // [kz4][y(stride 9)][i4 8] ~37KB
    __shared__ float2 twt[1024];     // [y][ky16] 8KB
    #pragma unroll 1
    for (int rep = 0; rep < REP; ++rep) {
        const float4* Tg4 = (const float4*)T1;
        size_t gbase = (size_t)(b * 16 + xx) * 64 * 256;
        #pragma unroll
        for (int t = threadIdx.x; t < 2048; t += 256) {
            int i4 = t & 7, kz4 = (t >> 3) & 3, y = t >> 5;
            sT4[kz4 * 576 + y * 9 + i4] =
                Tg4[gbase + (size_t)y * 256 + (kzg * 4 + kz4) * 16 + ih * 8 + i4];
        }
        const float cn = -2.0f * PI_F / 64.0f;
        for (int t = threadIdx.x; t < 1024; t += 256) {
            int y = t >> 4, ky = t & 15;
            float s, c; sincosf(cn * (float)((y * ky) & 63), &s, &c);
            twt[t] = make_float2(c, s);
        }
        __syncthreads();
        int ig = threadIdx.x & 7, ky2 = (threadIdx.x >> 3) & 7, kz4 = threadIdx.x >> 6;
        float ar[2][2], ai[2][2];
        #pragma unroll
        for (int h = 0; h < 2; h++) { ar[h][0] = ar[h][1] = ai[h][0] = ai[h][1] = 0.f; }
        const float4* twv = (const float4*)twt;
        #pragma unroll 8
        for (int y = 0; y < 64; y++) {
            float4 a  = sT4[kz4 * 576 + y * 9 + ig];   // (xr0,xi0,xr1,xi1)
            float4 tp = twv[y * 8 + ky2];              // (c0,s0,c1,s1)
            float xr[2] = {a.x, a.z}, xi[2] = {a.y, a.w};
            #pragma unroll
            for (int j = 0; j < 2; j++) {
                ar[0][j] += xr[j] * tp.x - xi[j] * tp.y;
                ai[0][j] += xr[j] * tp.y + xi[j] * tp.x;
                ar[1][j] += xr[j] * tp.z - xi[j] * tp.w;
                ai[1][j] += xr[j] * tp.w + xi[j] * tp.z;
            }
        }
        int kz = kzg * 4 + kz4;
        #pragma unroll
        for (int h = 0; h < 2; h++) {
            int ky = ky2 * 2 + h;
            float2* dp = XH + (((size_t)(b * 16 + xx) * 16 + ky) * 16 + kz) * 32 + ih * 16 + ig * 2;
            *(float4*)dp = make_float4(ar[h][0], ai[h][0], ar[h][1], ai[h][1]);
        }
        __syncthreads();
        asm volatile("" ::: "memory");
    }
}

// ---------------- K3: fused i-DFT + w-mul + o-IDFT -------------------------
// grid 256 = (x16, ky16); block 256; all 4 b handled via wave split.
__global__ __launch_bounds__(256) void k_mid(const float2* __restrict__ XH,
                                             const float* __restrict__ wr,
                                             const float* __restrict__ wi,
                                             float2* __restrict__ G) {
    int bid = blockIdx.x;
    int ky = bid & 15, xx = bid >> 4;
    __shared__ float2 sA[4 * 528];   // [b][kz(stride33)][i] ; reused as F[b][kz][o]
    __shared__ float2 sB[4 * 576];   // [b][ki(stride18)][kz]
    __shared__ float2 twt[1024];     // [m][k] = exp(-2pi i mk/32)
    #pragma unroll 1
    for (int rep = 0; rep < REP; ++rep) {
        for (int t = threadIdx.x; t < 2048; t += 256) {
            int b = t >> 9, kz = (t >> 5) & 15, i = t & 31;
            sA[b * 528 + kz * 33 + i] =
                XH[(((size_t)(b * 16 + xx) * 16 + ky) * 16 + kz) * 32 + i];
        }
        const float cn32 = -2.0f * PI_F / 32.0f;
        for (int t = threadIdx.x; t < 1024; t += 256) {
            int m = t >> 5, k = t & 31;
            float s, c; sincosf(cn32 * (float)((m * k) & 31), &s, &c);
            twt[t] = make_float2(c, s);
        }
        __syncthreads();
        const float4* twv = (const float4*)twt;
        // phase 1: X2[b][ki][kz] = sum_i tw[ki,i] * XH[b][kz][i]   (tile 8ki x 1kz)
        {
            int kz = threadIdx.x & 15, ki8 = (threadIdx.x >> 4) & 3, b = threadIdx.x >> 6;
            float xr[8], xi[8];
            #pragma unroll
            for (int j = 0; j < 8; j++) { xr[j] = xi[j] = 0.f; }
            #pragma unroll 4
            for (int i = 0; i < 32; i++) {
                float2 a = sA[b * 528 + kz * 33 + i];
                #pragma unroll
                for (int k = 0; k < 4; k++) {
                    float4 tp = twv[i * 16 + ki8 * 4 + k];
                    xr[2 * k]     += a.x * tp.x - a.y * tp.y;
                    xi[2 * k]     += a.x * tp.y + a.y * tp.x;
                    xr[2 * k + 1] += a.x * tp.z - a.y * tp.w;
                    xi[2 * k + 1] += a.x * tp.w + a.y * tp.z;
                }
            }
            #pragma unroll
            for (int j = 0; j < 8; j++)
                sB[b * 576 + (ki8 * 8 + j) * 18 + kz] = make_float2(xr[j], xi[j]);
        }
        __syncthreads();
        // phase 2: F[b][kz][o] = sum_ki X2[b][ki][kz] * w[ki,o]   (tile 2o x 4kz)
        {
            int kzg = threadIdx.x & 3, o2 = (threadIdx.x >> 2) & 15, b = threadIdx.x >> 6;
            int wbase = xx * 256 + ky * 16 + kzg * 4;
            float Fr[2][4], Fi[2][4];
            #pragma unroll
            for (int h = 0; h < 2; h++)
                #pragma unroll
                for (int q = 0; q < 4; q++) { Fr[h][q] = Fi[h][q] = 0.f; }
            const float4* sB4 = (const float4*)sB;
            #pragma unroll 4
            for (int ki = 0; ki < 32; ki++) {
                float4 a01 = sB4[b * 288 + ki * 9 + kzg * 2];
                float4 a23 = sB4[b * 288 + ki * 9 + kzg * 2 + 1];
                float xr[4] = {a01.x, a01.z, a23.x, a23.z};
                float xi[4] = {a01.y, a01.w, a23.y, a23.w};
                #pragma unroll
                for (int ol = 0; ol < 2; ol++) {
                    int o = o2 * 2 + ol;
                    float4 w4r = *(const float4*)(wr + (size_t)(ki * 32 + o) * 4096 + wbase);
                    float4 w4i = *(const float4*)(wi + (size_t)(ki * 32 + o) * 4096 + wbase);
                    float wrv[4] = {w4r.x, w4r.y, w4r.z, w4r.w};
                    float wiv[4] = {w4i.x, w4i.y, w4i.z, w4i.w};
                    #pragma unroll
                    for (int q = 0; q < 4; q++) {
                        Fr[ol][q] += xr[q] * wrv[q] - xi[q] * wiv[q];
                        Fi[ol][q] += xr[q] * wiv[q] + xi[q] * wrv[q];
                    }
                }
            }
            __syncthreads();
            #pragma unroll
            for (int ol = 0; ol < 2; ol++) {
                int o = o2 * 2 + ol;
                #pragma unroll
                for (int q = 0; q < 4; q++) {
                    int kz = kzg * 4 + q;
                    sA[b * 528 + kz * 33 + o] = make_float2(Fr[ol][q], Fi[ol][q]);
                }
            }
        }
        __syncthreads();
        // phase 3: G[b][kz][co] = sum_o conj(tw[co,o]) * F[b][kz][o]  (tile 8co x 1kz)
        {
            int kz = threadIdx.x & 15, co8 = (threadIdx.x >> 4) & 3, b = threadIdx.x >> 6;
            float gr[8], gi[8];
            #pragma unroll
            for (int j = 0; j < 8; j++) { gr[j] = gi[j] = 0.f; }
            #pragma unroll 4
            for (int o = 0; o < 32; o++) {
                float2 f = sA[b * 528 + kz * 33 + o];
                #pragma unroll
                for (int k = 0; k < 4; k++) {
                    float4 tp = twv[o * 16 + co8 * 4 + k];
                    gr[2 * k]     += f.x * tp.x + f.y * tp.y;
                    gi[2 * k]     += f.y * tp.x - f.x * tp.y;
                    gr[2 * k + 1] += f.x * tp.z + f.y * tp.w;
                    gi[2 * k + 1] += f.y * tp.z - f.x * tp.w;
                }
            }
            float2* dp = G + (((size_t)(b * 16 + xx) * 16 + ky) * 16 + kz) * 32 + co8 * 8;
            ((float4*)dp)[0] = make_float4(gr[0], gi[0], gr[1], gi[1]);
            ((float4*)dp)[1] = make_float4(gr[2], gi[2], gr[3], gi[3]);
            ((float4*)dp)[2] = make_float4(gr[4], gi[4], gr[5], gi[5]);
            ((float4*)dp)[3] = make_float4(gr[6], gi[6], gr[7], gi[7]);
        }
        __syncthreads();
        asm volatile("" ::: "memory");
    }
}

// ---------------- K4: fused z-IDFT + y-IDFT + Re + scale + zero-fill -------
// grid 2048 = (b4, x64, zc8); block 256. x>=16 -> pure zero-fill.
__global__ __launch_bounds__(256) void k_idft_zy(const float2* __restrict__ G,
                                                 float* __restrict__ out) {
    int bid = blockIdx.x;
    int zc = bid & 7, xx = (bid >> 3) & 63, b = bid >> 9;
    float* dstb = out + (size_t)(b * 64 + xx) * 131072;   // [y][z][co]
    if (xx >= 16) {
        #pragma unroll 1
        for (int rep = 0; rep < REP; ++rep) {
            float4* d4 = (float4*)dstb;
            for (int t = threadIdx.x; t < 4096; t += 256) {
                int y = t >> 6, r = t & 63;
                d4[(size_t)y * 512 + zc * 64 + r] = make_float4(0.f, 0.f, 0.f, 0.f);
            }
            asm volatile("" ::: "memory");
        }
        return;
    }
    __shared__ float2 sH[128 * 34];  // row R=ky*8+dz, stride 34, [co]  ~34KB
    __shared__ float2 twy[1024];     // [ky][y] 8KB
    __shared__ float2 twz[8 * 17];   // [dz][kz] padded
    #pragma unroll 1
    for (int rep = 0; rep < REP; ++rep) {
        const float cp = 2.0f * PI_F / 64.0f;
        for (int t = threadIdx.x; t < 1024; t += 256) {
            int ky = t >> 6, y = t & 63;
            float s, c; sincosf(cp * (float)((ky * y) & 63), &s, &c);
            twy[t] = make_float2(c, s);
        }
        if (threadIdx.x < 128) {
            int dz = threadIdx.x >> 4, kz = threadIdx.x & 15;
            int z = zc * 8 + dz;
            float s, c; sincosf(cp * (float)((kz * z) & 63), &s, &c);
            twz[dz * 17 + kz] = make_float2(c, s);
        }
        __syncthreads();
        // phase Z: H[ky][dz][co] = sum_kz twz[dz,kz] * G[ky][kz][co]
        {
            int coh = threadIdx.x & 1, dz = (threadIdx.x >> 1) & 7, ky = threadIdx.x >> 4;
            const float2* Gb = G + ((size_t)(b * 16 + xx) * 16 + ky) * 512 + coh * 16;
            float Hr[16], Hi[16];
            #pragma unroll
            for (int j = 0; j < 16; j++) { Hr[j] = Hi[j] = 0.f; }
            #pragma unroll 2
            for (int kz = 0; kz < 16; kz++) {
                float2 tz = twz[dz * 17 + kz];
                #pragma unroll
                for (int k = 0; k < 8; k++) {
                    float4 g = *(const float4*)(Gb + kz * 32 + k * 2);
                    Hr[2 * k]     += g.x * tz.x - g.y * tz.y;
                    Hi[2 * k]     += g.x * tz.y + g.y * tz.x;
                    Hr[2 * k + 1] += g.z * tz.x - g.w * tz.y;
                    Hi[2 * k + 1] += g.z * tz.y + g.w * tz.x;
                }
            }
            float2* hp = sH + (ky * 8 + dz) * 34 + coh * 16;
            #pragma unroll
            for (int k = 0; k < 8; k++)
                *(float4*)(hp + k * 2) = make_float4(Hr[2 * k], Hi[2 * k], Hr[2 * k + 1], Hi[2 * k + 1]);
        }
        __syncthreads();
        // phase Y: out[y][dz][co] = Re sum_ky twy[y,ky] * H[ky][dz][co]
        {
            int cog = threadIdx.x & 3, dz = (threadIdx.x >> 2) & 7, yg = threadIdx.x >> 5;
            float acc[8][8];
            #pragma unroll
            for (int yl = 0; yl < 8; yl++)
                #pragma unroll
                for (int cl = 0; cl < 8; cl++) acc[yl][cl] = 0.f;
            const float4* twy4 = (const float4*)twy;
            const float4* sH4 = (const float4*)sH;
            for (int ky = 0; ky < 16; ky++) {
                float4 t0 = twy4[ky * 32 + yg * 4 + 0];
                float4 t1 = twy4[ky * 32 + yg * 4 + 1];
                float4 t2 = twy4[ky * 32 + yg * 4 + 2];
                float4 t3 = twy4[ky * 32 + yg * 4 + 3];
                float4 h0 = sH4[(ky * 8 + dz) * 17 + cog * 4 + 0];
                float4 h1 = sH4[(ky * 8 + dz) * 17 + cog * 4 + 1];
                float4 h2 = sH4[(ky * 8 + dz) * 17 + cog * 4 + 2];
                float4 h3 = sH4[(ky * 8 + dz) * 17 + cog * 4 + 3];
                float tc[8] = {t0.x, t0.z, t1.x, t1.z, t2.x, t2.z, t3.x, t3.z};
                float ts[8] = {t0.y, t0.w, t1.y, t1.w, t2.y, t2.w, t3.y, t3.w};
                float hr[8] = {h0.x, h0.z, h1.x, h1.z, h2.x, h2.z, h3.x, h3.z};
                float hi[8] = {h0.y, h0.w, h1.y, h1.w, h2.y, h2.w, h3.y, h3.w};
                #pragma unroll
                for (int yl = 0; yl < 8; yl++)
                    #pragma unroll
                    for (int cl = 0; cl < 8; cl++)
                        acc[yl][cl] += tc[yl] * hr[cl] - ts[yl] * hi[cl];
            }
            const float sc = 1.0f / 131072.0f;
            #pragma unroll
            for (int yl = 0; yl < 8; yl++) {
                int y = yg * 8 + yl;
                float4* d4 = (float4*)(dstb + ((size_t)y * 64 + zc * 8 + dz) * 32 + cog * 8);
                d4[0] = make_float4(acc[yl][0] * sc, acc[yl][1] * sc, acc[yl][2] * sc, acc[yl][3] * sc);
                d4[1] = make_float4(acc[yl][4] * sc, acc[yl][5] * sc, acc[yl][6] * sc, acc[yl][7] * sc);
            }
        }
        __syncthreads();
        asm volatile("" ::: "memory");
    }
}

extern "C" void kernel_launch(void* const* d_in, const int* in_sizes, int n_in,
                              void* d_out, int out_size, void* d_ws, size_t ws_size,
                              hipStream_t stream) {
    const float* x  = (const float*)d_in[0];
    const float* wr = (const float*)d_in[1];
    const float* wi = (const float*)d_in[2];
    float* out = (float*)d_out;
    char*  ws  = (char*)d_ws;
    // T1: 2,097,152 f2 (16.8 MB); XH: 524,288 f2 (4.2 MB); G: 524,288 f2 (4.2 MB)
    float2* T1 = (float2*)ws;
    float2* XH = (float2*)(ws + (size_t)16777216);
    float2* Gb = (float2*)(ws + (size_t)16777216 + 4194304);

    k_dft_z  <<<1024, 256, 0, stream>>>(x, T1);
    k_dft_y  <<< 512, 256, 0, stream>>>(T1, XH);
    k_mid    <<< 256, 256, 0, stream>>>(XH, wr, wi, Gb);
    k_idft_zy<<<2048, 256, 0, stream>>>(Gb, out);
}

// Round 3
// 308.702 us; speedup vs baseline: 2.6508x; 2.6508x over previous
//
#include <hip/hip_runtime.h>
#include <math.h>

#define PI_F 3.14159265358979323846f

// Shapes: B=4, X=Y=Z=64, CIN=COUT=32, modes 16.
// Measured (REP-8 diagnostic): harness floor ~212us; kernels ~76us of which
// K4 ~37.5us, K1+K2+K3 ~38us. This round: K4 -> memset(zeros) + co-split
// active kernel (4 blk/CU); K3 -> 512 threads (2x waves, traffic-identical);
// K2 -> kz-split x2 (4 blk/CU, traffic-identical). K1 unchanged.

// ---------------- K1: forward z-DFT ----------------------------------------
// grid 1024 = (b4, x16, yg8, ih2); block 256; tile 2kz x 4i per thread.
__global__ __launch_bounds__(256) void k_dft_z(const float* __restrict__ x,
                                               float2* __restrict__ T1) {
    int bid = blockIdx.x;
    int ih = bid & 1, yg = (bid >> 1) & 7, xx = (bid >> 4) & 15, b = bid >> 8;
    __shared__ float  sx[8192];      // [y8][z64][i16] 32KB
    __shared__ float2 twt[1024];     // [z][kz16] 8KB
    float4* sx4 = (float4*)sx;
    const float4* src4 = (const float4*)(x + (size_t)((b * 64 + xx) * 64 + yg * 8) * 2048) + ih * 4;
    #pragma unroll
    for (int t = threadIdx.x; t < 2048; t += 256) {
        int i4 = t & 3, z = (t >> 2) & 63, y = t >> 8;
        sx4[(y * 64 + z) * 4 + i4] = src4[(size_t)y * 512 + z * 8 + i4];
    }
    const float cn = -2.0f * PI_F / 64.0f;
    for (int t = threadIdx.x; t < 1024; t += 256) {
        int z = t >> 4, kz = t & 15;
        float s, c; sincosf(cn * (float)((z * kz) & 63), &s, &c);
        twt[t] = make_float2(c, s);
    }
    __syncthreads();
    int ig = threadIdx.x & 3, kz2 = (threadIdx.x >> 2) & 7, y8 = threadIdx.x >> 5;
    float ar0[4], ai0[4], ar1[4], ai1[4];
    #pragma unroll
    for (int j = 0; j < 4; j++) { ar0[j] = ai0[j] = ar1[j] = ai1[j] = 0.f; }
    const float4* twv = (const float4*)twt;   // [z][8]: (c0,s0,c1,s1) per kz-pair
    #pragma unroll 8
    for (int z = 0; z < 64; z++) {
        float4 va = sx4[(y8 * 64 + z) * 4 + ig];
        float4 tp = twv[z * 8 + kz2];
        float v[4] = {va.x, va.y, va.z, va.w};
        #pragma unroll
        for (int j = 0; j < 4; j++) {
            ar0[j] = fmaf(v[j], tp.x, ar0[j]);
            ai0[j] = fmaf(v[j], tp.y, ai0[j]);
            ar1[j] = fmaf(v[j], tp.z, ar1[j]);
            ai1[j] = fmaf(v[j], tp.w, ai1[j]);
        }
    }
    int y = yg * 8 + y8, kz0 = kz2 * 2, i0 = ih * 16 + ig * 4;
    float2* dst = T1 + (size_t)((b * 16 + xx) * 64 + y) * 512;
    float4* d0 = (float4*)(dst + kz0 * 32 + i0);
    d0[0] = make_float4(ar0[0], ai0[0], ar0[1], ai0[1]);
    d0[1] = make_float4(ar0[2], ai0[2], ar0[3], ai0[3]);
    float4* d1 = (float4*)(dst + (kz0 + 1) * 32 + i0);
    d1[0] = make_float4(ar1[0], ai1[0], ar1[1], ai1[1]);
    d1[1] = make_float4(ar1[2], ai1[2], ar1[3], ai1[3]);
}

// ---------------- K2: forward y-DFT ----------------------------------------
// grid 1024 = (b4, x16, kzg8, ih2); block 256; 1ky x 2i per thread.
// Traffic-identical to baseline (T1 read once, coalesced 128B segments).
__global__ __launch_bounds__(256) void k_dft_y(const float2* __restrict__ T1,
                                               float2* __restrict__ XH) {
    int bid = blockIdx.x;
    int ih = bid & 1, kzg = (bid >> 1) & 7, xx = (bid >> 4) & 15, b = bid >> 8;
    __shared__ float4 sT4[2 * 576];  // [kz2][y(stride 9)][i4 8] ~18.4KB
    __shared__ float2 twt[1024];     // [y][ky16] 8KB
    const float4* Tg4 = (const float4*)T1;
    size_t gbase = (size_t)(b * 16 + xx) * 64 * 256;
    #pragma unroll
    for (int t = threadIdx.x; t < 1024; t += 256) {
        int i4 = t & 7, kzl = (t >> 3) & 1, y = t >> 4;
        sT4[kzl * 576 + y * 9 + i4] =
            Tg4[gbase + (size_t)y * 256 + (kzg * 2 + kzl) * 16 + ih * 8 + i4];
    }
    const float cn = -2.0f * PI_F / 64.0f;
    for (int t = threadIdx.x; t < 1024; t += 256) {
        int y = t >> 4, ky = t & 15;
        float s, c; sincosf(cn * (float)((y * ky) & 63), &s, &c);
        twt[t] = make_float2(c, s);
    }
    __syncthreads();
    int ig = threadIdx.x & 7, kzl = (threadIdx.x >> 3) & 1, ky = threadIdx.x >> 4;
    float ar0 = 0.f, ai0 = 0.f, ar1 = 0.f, ai1 = 0.f;
    #pragma unroll 8
    for (int y = 0; y < 64; y++) {
        float4 a  = sT4[kzl * 576 + y * 9 + ig];   // (xr0,xi0,xr1,xi1)
        float2 tp = twt[y * 16 + ky];
        ar0 += a.x * tp.x - a.y * tp.y;
        ai0 += a.x * tp.y + a.y * tp.x;
        ar1 += a.z * tp.x - a.w * tp.y;
        ai1 += a.z * tp.y + a.w * tp.x;
    }
    int kz = kzg * 2 + kzl;
    float2* dp = XH + (((size_t)(b * 16 + xx) * 16 + ky) * 16 + kz) * 32 + ih * 16 + ig * 2;
    *(float4*)dp = make_float4(ar0, ai0, ar1, ai1);
}

// ---------------- K3: fused i-DFT + w-mul + o-IDFT -------------------------
// grid 256 = (x16, ky16); block 512 (2x waves/CU vs baseline, same traffic:
// weights read ONCE as full 64B lines). Per-thread tiles: 4ki / 1o x 4kz / 4co.
__global__ __launch_bounds__(512) void k_mid(const float2* __restrict__ XH,
                                             const float* __restrict__ wr,
                                             const float* __restrict__ wi,
                                             float2* __restrict__ G) {
    int bid = blockIdx.x;
    int ky = bid & 15, xx = bid >> 4;
    __shared__ float2 sA[4 * 528];   // [b][kz(stride33)][i] ; reused as F[b][kz][o]
    __shared__ float2 sB[4 * 576];   // [b][ki(stride18)][kz]
    __shared__ float2 twt[1024];     // [m][k] = exp(-2pi i mk/32)
    for (int t = threadIdx.x; t < 2048; t += 512) {
        int b = t >> 9, kz = (t >> 5) & 15, i = t & 31;
        sA[b * 528 + kz * 33 + i] =
            XH[(((size_t)(b * 16 + xx) * 16 + ky) * 16 + kz) * 32 + i];
    }
    const float cn32 = -2.0f * PI_F / 32.0f;
    for (int t = threadIdx.x; t < 1024; t += 512) {
        int m = t >> 5, k = t & 31;
        float s, c; sincosf(cn32 * (float)((m * k) & 31), &s, &c);
        twt[t] = make_float2(c, s);
    }
    __syncthreads();
    const float4* twv = (const float4*)twt;
    // phase 1: X2[b][ki][kz] = sum_i tw[ki,i] * XH[b][kz][i]  (4ki x 1kz per thread)
    {
        int kz = threadIdx.x & 15, kig = (threadIdx.x >> 4) & 7, b = threadIdx.x >> 7;
        float xr[4], xi[4];
        #pragma unroll
        for (int j = 0; j < 4; j++) { xr[j] = xi[j] = 0.f; }
        #pragma unroll 8
        for (int i = 0; i < 32; i++) {
            float2 a   = sA[b * 528 + kz * 33 + i];
            float4 tp0 = twv[i * 16 + kig * 2];       // ki = kig*4+0,1
            float4 tp1 = twv[i * 16 + kig * 2 + 1];   // ki = kig*4+2,3
            xr[0] += a.x * tp0.x - a.y * tp0.y;  xi[0] += a.x * tp0.y + a.y * tp0.x;
            xr[1] += a.x * tp0.z - a.y * tp0.w;  xi[1] += a.x * tp0.w + a.y * tp0.z;
            xr[2] += a.x * tp1.x - a.y * tp1.y;  xi[2] += a.x * tp1.y + a.y * tp1.x;
            xr[3] += a.x * tp1.z - a.y * tp1.w;  xi[3] += a.x * tp1.w + a.y * tp1.z;
        }
        #pragma unroll
        for (int j = 0; j < 4; j++)
            sB[b * 576 + (kig * 4 + j) * 18 + kz] = make_float2(xr[j], xi[j]);
    }
    __syncthreads();
    // phase 2: F[b][kz][o] = sum_ki X2[b][ki][kz] * w[ki,o]  (1o x 4kz per thread)
    {
        int kzg = threadIdx.x & 3, o = (threadIdx.x >> 2) & 31, b = threadIdx.x >> 7;
        int wbase = xx * 256 + ky * 16 + kzg * 4;
        float Fr[4], Fi[4];
        #pragma unroll
        for (int q = 0; q < 4; q++) { Fr[q] = Fi[q] = 0.f; }
        const float4* sB4 = (const float4*)sB;     // f4 stride 9 per ki
        #pragma unroll 4
        for (int ki = 0; ki < 32; ki++) {
            float4 a01 = sB4[b * 288 + ki * 9 + kzg * 2];
            float4 a23 = sB4[b * 288 + ki * 9 + kzg * 2 + 1];
            float4 w4r = *(const float4*)(wr + (size_t)(ki * 32 + o) * 4096 + wbase);
            float4 w4i = *(const float4*)(wi + (size_t)(ki * 32 + o) * 4096 + wbase);
            float xr[4]  = {a01.x, a01.z, a23.x, a23.z};
            float xi[4]  = {a01.y, a01.w, a23.y, a23.w};
            float wrv[4] = {w4r.x, w4r.y, w4r.z, w4r.w};
            float wiv[4] = {w4i.x, w4i.y, w4i.z, w4i.w};
            #pragma unroll
            for (int q = 0; q < 4; q++) {
                Fr[q] += xr[q] * wrv[q] - xi[q] * wiv[q];
                Fi[q] += xr[q] * wiv[q] + xi[q] * wrv[q];
            }
        }
        #pragma unroll
        for (int q = 0; q < 4; q++) {
            int kz = kzg * 4 + q;
            sA[b * 528 + kz * 33 + o] = make_float2(Fr[q], Fi[q]);
        }
    }
    __syncthreads();
    // phase 3: G[b][kz][co] = sum_o conj(tw[co,o]) * F[b][kz][o] (4co x 1kz per thread)
    {
        int kz = threadIdx.x & 15, cog = (threadIdx.x >> 4) & 7, b = threadIdx.x >> 7;
        float gr[4], gi[4];
        #pragma unroll
        for (int j = 0; j < 4; j++) { gr[j] = gi[j] = 0.f; }
        #pragma unroll 8
        for (int o = 0; o < 32; o++) {
            float2 f   = sA[b * 528 + kz * 33 + o];
            float4 tp0 = twv[o * 16 + cog * 2];       // co = cog*4+0,1
            float4 tp1 = twv[o * 16 + cog * 2 + 1];   // co = cog*4+2,3
            gr[0] += f.x * tp0.x + f.y * tp0.y;  gi[0] += f.y * tp0.x - f.x * tp0.y;
            gr[1] += f.x * tp0.z + f.y * tp0.w;  gi[1] += f.y * tp0.z - f.x * tp0.w;
            gr[2] += f.x * tp1.x + f.y * tp1.y;  gi[2] += f.y * tp1.x - f.x * tp1.y;
            gr[3] += f.x * tp1.z + f.y * tp1.w;  gi[3] += f.y * tp1.z - f.x * tp1.w;
        }
        float2* dp = G + (((size_t)(b * 16 + xx) * 16 + ky) * 16 + kz) * 32 + cog * 4;
        ((float4*)dp)[0] = make_float4(gr[0], gi[0], gr[1], gi[1]);
        ((float4*)dp)[1] = make_float4(gr[2], gi[2], gr[3], gi[3]);
    }
}

// ---------------- K4: fused z-IDFT + y-IDFT + Re + scale (active x only) ---
// grid 1024 = (b4, x16, zc8, ch2); block 256. Zero region handled by memset.
// LDS ~27.5KB -> 4 blk/CU co-resident (16 waves/CU).
__global__ __launch_bounds__(256) void k_idft_zy(const float2* __restrict__ G,
                                                 float* __restrict__ out) {
    int bid = blockIdx.x;
    int ch = bid & 1, zc = (bid >> 1) & 7, xx = (bid >> 4) & 15, b = bid >> 8;
    float* dstb = out + (size_t)(b * 64 + xx) * 131072;   // [y][z][co]
    __shared__ float2 sH[128 * 18];  // row R=ky*8+dz, stride 18, [co16]  ~18.4KB
    __shared__ float2 twy[1024];     // [ky][y] 8KB
    __shared__ float2 twz[8 * 17];   // [dz][kz] padded
    const float cp = 2.0f * PI_F / 64.0f;
    for (int t = threadIdx.x; t < 1024; t += 256) {
        int ky = t >> 6, y = t & 63;
        float s, c; sincosf(cp * (float)((ky * y) & 63), &s, &c);
        twy[t] = make_float2(c, s);
    }
    if (threadIdx.x < 128) {
        int dz = threadIdx.x >> 4, kz = threadIdx.x & 15;
        int z = zc * 8 + dz;
        float s, c; sincosf(cp * (float)((kz * z) & 63), &s, &c);
        twz[dz * 17 + kz] = make_float2(c, s);
    }
    __syncthreads();
    // phase Z: H[ky][dz][co16] = sum_kz twz[dz,kz] * G[ky][kz][co-half]
    {
        int coq = threadIdx.x & 1, dz = (threadIdx.x >> 1) & 7, ky = threadIdx.x >> 4;
        const float2* Gb = G + ((size_t)(b * 16 + xx) * 16 + ky) * 512 + ch * 16 + coq * 8;
        float Hr[8], Hi[8];
        #pragma unroll
        for (int j = 0; j < 8; j++) { Hr[j] = Hi[j] = 0.f; }
        #pragma unroll 4
        for (int kz = 0; kz < 16; kz++) {
            float2 tz = twz[dz * 17 + kz];
            #pragma unroll
            for (int k = 0; k < 4; k++) {
                float4 g = *(const float4*)(Gb + kz * 32 + k * 2);
                Hr[2 * k]     += g.x * tz.x - g.y * tz.y;
                Hi[2 * k]     += g.x * tz.y + g.y * tz.x;
                Hr[2 * k + 1] += g.z * tz.x - g.w * tz.y;
                Hi[2 * k + 1] += g.z * tz.y + g.w * tz.x;
            }
        }
        float2* hp = sH + (ky * 8 + dz) * 18 + coq * 8;
        #pragma unroll
        for (int k = 0; k < 4; k++)
            *(float4*)(hp + k * 2) = make_float4(Hr[2 * k], Hi[2 * k], Hr[2 * k + 1], Hi[2 * k + 1]);
    }
    __syncthreads();
    // phase Y: out[y][dz][co16] = Re sum_ky twy[y,ky] * H[ky][dz][co16]
    {
        int cog = threadIdx.x & 1, dz = (threadIdx.x >> 1) & 7, yg = threadIdx.x >> 4;
        float acc[4][8];
        #pragma unroll
        for (int yl = 0; yl < 4; yl++)
            #pragma unroll
            for (int cl = 0; cl < 8; cl++) acc[yl][cl] = 0.f;
        const float4* twy4 = (const float4*)twy;
        const float4* sH4 = (const float4*)sH;    // f4 stride 9 per row
        for (int ky = 0; ky < 16; ky++) {
            float4 t0 = twy4[ky * 32 + yg * 2 + 0];
            float4 t1 = twy4[ky * 32 + yg * 2 + 1];
            float4 h0 = sH4[(ky * 8 + dz) * 9 + cog * 4 + 0];
            float4 h1 = sH4[(ky * 8 + dz) * 9 + cog * 4 + 1];
            float4 h2 = sH4[(ky * 8 + dz) * 9 + cog * 4 + 2];
            float4 h3 = sH4[(ky * 8 + dz) * 9 + cog * 4 + 3];
            float tc[4] = {t0.x, t0.z, t1.x, t1.z};
            float ts[4] = {t0.y, t0.w, t1.y, t1.w};
            float hr[8] = {h0.x, h0.z, h1.x, h1.z, h2.x, h2.z, h3.x, h3.z};
            float hi[8] = {h0.y, h0.w, h1.y, h1.w, h2.y, h2.w, h3.y, h3.w};
            #pragma unroll
            for (int yl = 0; yl < 4; yl++)
                #pragma unroll
                for (int cl = 0; cl < 8; cl++)
                    acc[yl][cl] += tc[yl] * hr[cl] - ts[yl] * hi[cl];
        }
        const float sc = 1.0f / 131072.0f;
        #pragma unroll
        for (int yl = 0; yl < 4; yl++) {
            int y = yg * 4 + yl;
            float4* d4 = (float4*)(dstb + ((size_t)y * 64 + zc * 8 + dz) * 32 + ch * 16 + cog * 8);
            d4[0] = make_float4(acc[yl][0] * sc, acc[yl][1] * sc, acc[yl][2] * sc, acc[yl][3] * sc);
            d4[1] = make_float4(acc[yl][4] * sc, acc[yl][5] * sc, acc[yl][6] * sc, acc[yl][7] * sc);
        }
    }
}

extern "C" void kernel_launch(void* const* d_in, const int* in_sizes, int n_in,
                              void* d_out, int out_size, void* d_ws, size_t ws_size,
                              hipStream_t stream) {
    const float* x  = (const float*)d_in[0];
    const float* wr = (const float*)d_in[1];
    const float* wi = (const float*)d_in[2];
    float* out = (float*)d_out;
    char*  ws  = (char*)d_ws;
    // T1: 2,097,152 f2 (16.8 MB); XH: 524,288 f2 (4.2 MB); G: 524,288 f2 (4.2 MB)
    float2* T1 = (float2*)ws;
    float2* XH = (float2*)(ws + (size_t)16777216);
    float2* Gb = (float2*)(ws + (size_t)16777216 + 4194304);

    // zero-fill x>=16 output region (contiguous 25.2MB per b) at fill-kernel BW
    for (int b = 0; b < 4; ++b)
        hipMemsetAsync(out + ((size_t)b * 64 + 16) * 131072, 0,
                       (size_t)48 * 131072 * sizeof(float), stream);

    k_dft_z  <<<1024, 256, 0, stream>>>(x, T1);
    k_dft_y  <<<1024, 256, 0, stream>>>(T1, XH);
    k_mid    <<< 256, 512, 0, stream>>>(XH, wr, wi, Gb);
    k_idft_zy<<<1024, 256, 0, stream>>>(Gb, out);
}

// Round 4
// 290.969 us; speedup vs baseline: 2.8123x; 1.0609x over previous
//
#include <hip/hip_runtime.h>
#include <math.h>

#define PI_F 3.14159265358979323846f

// Shapes: B=4, X=Y=Z=64, CIN=COUT=32, modes 16.
// Round-4 structure (baseline K2/K3; fill fused into K1; K4 active-only):
//  K1 z-DFT + zero-fill: blocks <1024 do the z-DFT (baseline code);
//                        blocks >=1024 stream zeros into out[x>=16] (100 MB),
//                        overlapping K1..K3's unused write BW.
//  K2 y-DFT   : baseline (grid 512, 37KB LDS).
//  K3 fused   : baseline (grid 256, block 256).
//  K4 fused   : z-IDFT + y-IDFT + Re + scale, ACTIVE x<16 only, co-half split
//               (grid 1024, LDS 27.5KB -> 4-5 blk/CU).

// ---------------- K1: forward z-DFT + output zero-fill ---------------------
// grid 2560 = 1024 dft (b4, x16, yg8, ih2) + 1536 fill; block 256.
__global__ __launch_bounds__(256) void k_dft_z(const float* __restrict__ x,
                                               float2* __restrict__ T1,
                                               float* __restrict__ out) {
    int bid = blockIdx.x;
    if (bid >= 1024) {
        // zero-fill out[b][16..63][*][*][*]: 1536 blocks x 64KB contiguous.
        int f = bid - 1024;
        int b = f / 384, rem = f - b * 384;
        float4* d4 = (float4*)(out + (size_t)(b * 64 + 16) * 131072) + (size_t)rem * 4096;
        #pragma unroll
        for (int r = 0; r < 16; ++r)
            d4[r * 256 + threadIdx.x] = make_float4(0.f, 0.f, 0.f, 0.f);
        return;
    }
    int ih = bid & 1, yg = (bid >> 1) & 7, xx = (bid >> 4) & 15, b = bid >> 8;
    __shared__ float  sx[8192];      // [y8][z64][i16] 32KB
    __shared__ float2 twt[1024];     // [z][kz16] 8KB
    float4* sx4 = (float4*)sx;
    const float4* src4 = (const float4*)(x + (size_t)((b * 64 + xx) * 64 + yg * 8) * 2048) + ih * 4;
    #pragma unroll
    for (int t = threadIdx.x; t < 2048; t += 256) {
        int i4 = t & 3, z = (t >> 2) & 63, y = t >> 8;
        sx4[(y * 64 + z) * 4 + i4] = src4[(size_t)y * 512 + z * 8 + i4];
    }
    const float cn = -2.0f * PI_F / 64.0f;
    for (int t = threadIdx.x; t < 1024; t += 256) {
        int z = t >> 4, kz = t & 15;
        float s, c; sincosf(cn * (float)((z * kz) & 63), &s, &c);
        twt[t] = make_float2(c, s);
    }
    __syncthreads();
    int ig = threadIdx.x & 3, kz2 = (threadIdx.x >> 2) & 7, y8 = threadIdx.x >> 5;
    float ar0[4], ai0[4], ar1[4], ai1[4];
    #pragma unroll
    for (int j = 0; j < 4; j++) { ar0[j] = ai0[j] = ar1[j] = ai1[j] = 0.f; }
    const float4* twv = (const float4*)twt;   // [z][8]: (c0,s0,c1,s1) per kz-pair
    #pragma unroll 8
    for (int z = 0; z < 64; z++) {
        float4 va = sx4[(y8 * 64 + z) * 4 + ig];
        float4 tp = twv[z * 8 + kz2];
        float v[4] = {va.x, va.y, va.z, va.w};
        #pragma unroll
        for (int j = 0; j < 4; j++) {
            ar0[j] = fmaf(v[j], tp.x, ar0[j]);
            ai0[j] = fmaf(v[j], tp.y, ai0[j]);
            ar1[j] = fmaf(v[j], tp.z, ar1[j]);
            ai1[j] = fmaf(v[j], tp.w, ai1[j]);
        }
    }
    int y = yg * 8 + y8, kz0 = kz2 * 2, i0 = ih * 16 + ig * 4;
    float2* dst = T1 + (size_t)((b * 16 + xx) * 64 + y) * 512;
    float4* d0 = (float4*)(dst + kz0 * 32 + i0);
    d0[0] = make_float4(ar0[0], ai0[0], ar0[1], ai0[1]);
    d0[1] = make_float4(ar0[2], ai0[2], ar0[3], ai0[3]);
    float4* d1 = (float4*)(dst + (kz0 + 1) * 32 + i0);
    d1[0] = make_float4(ar1[0], ai1[0], ar1[1], ai1[1]);
    d1[1] = make_float4(ar1[2], ai1[2], ar1[3], ai1[3]);
}

// ---------------- K2: forward y-DFT (baseline) -----------------------------
// grid 512 = (b4, x16, kzg4, ih2); block 256; tile 2ky x 2i per thread.
__global__ __launch_bounds__(256) void k_dft_y(const float2* __restrict__ T1,
                                               float2* __restrict__ XH) {
    int bid = blockIdx.x;
    int ih = bid & 1, kzg = (bid >> 1) & 3, xx = (bid >> 3) & 15, b = bid >> 7;
    __shared__ float4 sT4[2304];     // [kz4][y(stride 9)][i4 8] ~37KB
    __shared__ float2 twt[1024];     // [y][ky16] 8KB
    const float4* Tg4 = (const float4*)T1;
    size_t gbase = (size_t)(b * 16 + xx) * 64 * 256;
    #pragma unroll
    for (int t = threadIdx.x; t < 2048; t += 256) {
        int i4 = t & 7, kz4 = (t >> 3) & 3, y = t >> 5;
        sT4[kz4 * 576 + y * 9 + i4] =
            Tg4[gbase + (size_t)y * 256 + (kzg * 4 + kz4) * 16 + ih * 8 + i4];
    }
    const float cn = -2.0f * PI_F / 64.0f;
    for (int t = threadIdx.x; t < 1024; t += 256) {
        int y = t >> 4, ky = t & 15;
        float s, c; sincosf(cn * (float)((y * ky) & 63), &s, &c);
        twt[t] = make_float2(c, s);
    }
    __syncthreads();
    int ig = threadIdx.x & 7, ky2 = (threadIdx.x >> 3) & 7, kz4 = threadIdx.x >> 6;
    float ar[2][2], ai[2][2];
    #pragma unroll
    for (int h = 0; h < 2; h++) { ar[h][0] = ar[h][1] = ai[h][0] = ai[h][1] = 0.f; }
    const float4* twv = (const float4*)twt;
    #pragma unroll 8
    for (int y = 0; y < 64; y++) {
        float4 a  = sT4[kz4 * 576 + y * 9 + ig];   // (xr0,xi0,xr1,xi1)
        float4 tp = twv[y * 8 + ky2];              // (c0,s0,c1,s1)
        float xr[2] = {a.x, a.z}, xi[2] = {a.y, a.w};
        #pragma unroll
        for (int j = 0; j < 2; j++) {
            ar[0][j] += xr[j] * tp.x - xi[j] * tp.y;
            ai[0][j] += xr[j] * tp.y + xi[j] * tp.x;
            ar[1][j] += xr[j] * tp.z - xi[j] * tp.w;
            ai[1][j] += xr[j] * tp.w + xi[j] * tp.z;
        }
    }
    int kz = kzg * 4 + kz4;
    #pragma unroll
    for (int h = 0; h < 2; h++) {
        int ky = ky2 * 2 + h;
        float2* dp = XH + (((size_t)(b * 16 + xx) * 16 + ky) * 16 + kz) * 32 + ih * 16 + ig * 2;
        *(float4*)dp = make_float4(ar[h][0], ai[h][0], ar[h][1], ai[h][1]);
    }
}

// ---------------- K3: fused i-DFT + w-mul + o-IDFT (baseline) --------------
// grid 256 = (x16, ky16); block 256; all 4 b handled via wave split.
__global__ __launch_bounds__(256) void k_mid(const float2* __restrict__ XH,
                                             const float* __restrict__ wr,
                                             const float* __restrict__ wi,
                                             float2* __restrict__ G) {
    int bid = blockIdx.x;
    int ky = bid & 15, xx = bid >> 4;
    __shared__ float2 sA[4 * 528];   // [b][kz(stride33)][i] ; reused as F[b][kz][o]
    __shared__ float2 sB[4 * 576];   // [b][ki(stride18)][kz]
    __shared__ float2 twt[1024];     // [m][k] = exp(-2pi i mk/32)
    for (int t = threadIdx.x; t < 2048; t += 256) {
        int b = t >> 9, kz = (t >> 5) & 15, i = t & 31;
        sA[b * 528 + kz * 33 + i] =
            XH[(((size_t)(b * 16 + xx) * 16 + ky) * 16 + kz) * 32 + i];
    }
    const float cn32 = -2.0f * PI_F / 32.0f;
    for (int t = threadIdx.x; t < 1024; t += 256) {
        int m = t >> 5, k = t & 31;
        float s, c; sincosf(cn32 * (float)((m * k) & 31), &s, &c);
        twt[t] = make_float2(c, s);
    }
    __syncthreads();
    const float4* twv = (const float4*)twt;
    // phase 1: X2[b][ki][kz] = sum_i tw[ki,i] * XH[b][kz][i]   (tile 8ki x 1kz)
    {
        int kz = threadIdx.x & 15, ki8 = (threadIdx.x >> 4) & 3, b = threadIdx.x >> 6;
        float xr[8], xi[8];
        #pragma unroll
        for (int j = 0; j < 8; j++) { xr[j] = xi[j] = 0.f; }
        #pragma unroll 4
        for (int i = 0; i < 32; i++) {
            float2 a = sA[b * 528 + kz * 33 + i];
            #pragma unroll
            for (int k = 0; k < 4; k++) {
                float4 tp = twv[i * 16 + ki8 * 4 + k];
                xr[2 * k]     += a.x * tp.x - a.y * tp.y;
                xi[2 * k]     += a.x * tp.y + a.y * tp.x;
                xr[2 * k + 1] += a.x * tp.z - a.y * tp.w;
                xi[2 * k + 1] += a.x * tp.w + a.y * tp.z;
            }
        }
        #pragma unroll
        for (int j = 0; j < 8; j++)
            sB[b * 576 + (ki8 * 8 + j) * 18 + kz] = make_float2(xr[j], xi[j]);
    }
    __syncthreads();
    // phase 2: F[b][kz][o] = sum_ki X2[b][ki][kz] * w[ki,o]   (tile 2o x 4kz)
    {
        int kzg = threadIdx.x & 3, o2 = (threadIdx.x >> 2) & 15, b = threadIdx.x >> 6;
        int wbase = xx * 256 + ky * 16 + kzg * 4;
        float Fr[2][4], Fi[2][4];
        #pragma unroll
        for (int h = 0; h < 2; h++)
            #pragma unroll
            for (int q = 0; q < 4; q++) { Fr[h][q] = Fi[h][q] = 0.f; }
        const float4* sB4 = (const float4*)sB;
        #pragma unroll 4
        for (int ki = 0; ki < 32; ki++) {
            float4 a01 = sB4[b * 288 + ki * 9 + kzg * 2];
            float4 a23 = sB4[b * 288 + ki * 9 + kzg * 2 + 1];
            float xr[4] = {a01.x, a01.z, a23.x, a23.z};
            float xi[4] = {a01.y, a01.w, a23.y, a23.w};
            #pragma unroll
            for (int ol = 0; ol < 2; ol++) {
                int o = o2 * 2 + ol;
                float4 w4r = *(const float4*)(wr + (size_t)(ki * 32 + o) * 4096 + wbase);
                float4 w4i = *(const float4*)(wi + (size_t)(ki * 32 + o) * 4096 + wbase);
                float wrv[4] = {w4r.x, w4r.y, w4r.z, w4r.w};
                float wiv[4] = {w4i.x, w4i.y, w4i.z, w4i.w};
                #pragma unroll
                for (int q = 0; q < 4; q++) {
                    Fr[ol][q] += xr[q] * wrv[q] - xi[q] * wiv[q];
                    Fi[ol][q] += xr[q] * wiv[q] + xi[q] * wrv[q];
                }
            }
        }
        __syncthreads();
        #pragma unroll
        for (int ol = 0; ol < 2; ol++) {
            int o = o2 * 2 + ol;
            #pragma unroll
            for (int q = 0; q < 4; q++) {
                int kz = kzg * 4 + q;
                sA[b * 528 + kz * 33 + o] = make_float2(Fr[ol][q], Fi[ol][q]);
            }
        }
    }
    __syncthreads();
    // phase 3: G[b][kz][co] = sum_o conj(tw[co,o]) * F[b][kz][o]  (tile 8co x 1kz)
    {
        int kz = threadIdx.x & 15, co8 = (threadIdx.x >> 4) & 3, b = threadIdx.x >> 6;
        float gr[8], gi[8];
        #pragma unroll
        for (int j = 0; j < 8; j++) { gr[j] = gi[j] = 0.f; }
        #pragma unroll 4
        for (int o = 0; o < 32; o++) {
            float2 f = sA[b * 528 + kz * 33 + o];
            #pragma unroll
            for (int k = 0; k < 4; k++) {
                float4 tp = twv[o * 16 + co8 * 4 + k];
                gr[2 * k]     += f.x * tp.x + f.y * tp.y;
                gi[2 * k]     += f.y * tp.x - f.x * tp.y;
                gr[2 * k + 1] += f.x * tp.z + f.y * tp.w;
                gi[2 * k + 1] += f.y * tp.z - f.x * tp.w;
            }
        }
        float2* dp = G + (((size_t)(b * 16 + xx) * 16 + ky) * 16 + kz) * 32 + co8 * 8;
        ((float4*)dp)[0] = make_float4(gr[0], gi[0], gr[1], gi[1]);
        ((float4*)dp)[1] = make_float4(gr[2], gi[2], gr[3], gi[3]);
        ((float4*)dp)[2] = make_float4(gr[4], gi[4], gr[5], gi[5]);
        ((float4*)dp)[3] = make_float4(gr[6], gi[6], gr[7], gi[7]);
    }
}

// ---------------- K4: fused z-IDFT + y-IDFT + Re + scale (active x only) ---
// grid 1024 = (b4, x16, zc8, ch2); block 256. Zero region handled by K1 fill.
// LDS ~27.5KB -> 4-5 blk/CU co-resident.
__global__ __launch_bounds__(256) void k_idft_zy(const float2* __restrict__ G,
                                                 float* __restrict__ out) {
    int bid = blockIdx.x;
    int ch = bid & 1, zc = (bid >> 1) & 7, xx = (bid >> 4) & 15, b = bid >> 8;
    float* dstb = out + (size_t)(b * 64 + xx) * 131072;   // [y][z][co]
    __shared__ float2 sH[128 * 18];  // row R=ky*8+dz, stride 18, [co16]  ~18.4KB
    __shared__ float2 twy[1024];     // [ky][y] 8KB
    __shared__ float2 twz[8 * 17];   // [dz][kz] padded
    const float cp = 2.0f * PI_F / 64.0f;
    for (int t = threadIdx.x; t < 1024; t += 256) {
        int ky = t >> 6, y = t & 63;
        float s, c; sincosf(cp * (float)((ky * y) & 63), &s, &c);
        twy[t] = make_float2(c, s);
    }
    if (threadIdx.x < 128) {
        int dz = threadIdx.x >> 4, kz = threadIdx.x & 15;
        int z = zc * 8 + dz;
        float s, c; sincosf(cp * (float)((kz * z) & 63), &s, &c);
        twz[dz * 17 + kz] = make_float2(c, s);
    }
    __syncthreads();
    // phase Z: H[ky][dz][co16] = sum_kz twz[dz,kz] * G[ky][kz][co-half]
    {
        int coq = threadIdx.x & 1, dz = (threadIdx.x >> 1) & 7, ky = threadIdx.x >> 4;
        const float2* Gb = G + ((size_t)(b * 16 + xx) * 16 + ky) * 512 + ch * 16 + coq * 8;
        float Hr[8], Hi[8];
        #pragma unroll
        for (int j = 0; j < 8; j++) { Hr[j] = Hi[j] = 0.f; }
        #pragma unroll 4
        for (int kz = 0; kz < 16; kz++) {
            float2 tz = twz[dz * 17 + kz];
            #pragma unroll
            for (int k = 0; k < 4; k++) {
                float4 g = *(const float4*)(Gb + kz * 32 + k * 2);
                Hr[2 * k]     += g.x * tz.x - g.y * tz.y;
                Hi[2 * k]     += g.x * tz.y + g.y * tz.x;
                Hr[2 * k + 1] += g.z * tz.x - g.w * tz.y;
                Hi[2 * k + 1] += g.z * tz.y + g.w * tz.x;
            }
        }
        float2* hp = sH + (ky * 8 + dz) * 18 + coq * 8;
        #pragma unroll
        for (int k = 0; k < 4; k++)
            *(float4*)(hp + k * 2) = make_float4(Hr[2 * k], Hi[2 * k], Hr[2 * k + 1], Hi[2 * k + 1]);
    }
    __syncthreads();
    // phase Y: out[y][dz][co16] = Re sum_ky twy[y,ky] * H[ky][dz][co16]
    {
        int cog = threadIdx.x & 1, dz = (threadIdx.x >> 1) & 7, yg = threadIdx.x >> 4;
        float acc[4][8];
        #pragma unroll
        for (int yl = 0; yl < 4; yl++)
            #pragma unroll
            for (int cl = 0; cl < 8; cl++) acc[yl][cl] = 0.f;
        const float4* twy4 = (const float4*)twy;
        const float4* sH4 = (const float4*)sH;    // f4 stride 9 per row
        for (int ky = 0; ky < 16; ky++) {
            float4 t0 = twy4[ky * 32 + yg * 2 + 0];
            float4 t1 = twy4[ky * 32 + yg * 2 + 1];
            float4 h0 = sH4[(ky * 8 + dz) * 9 + cog * 4 + 0];
            float4 h1 = sH4[(ky * 8 + dz) * 9 + cog * 4 + 1];
            float4 h2 = sH4[(ky * 8 + dz) * 9 + cog * 4 + 2];
            float4 h3 = sH4[(ky * 8 + dz) * 9 + cog * 4 + 3];
            float tc[4] = {t0.x, t0.z, t1.x, t1.z};
            float ts[4] = {t0.y, t0.w, t1.y, t1.w};
            float hr[8] = {h0.x, h0.z, h1.x, h1.z, h2.x, h2.z, h3.x, h3.z};
            float hi[8] = {h0.y, h0.w, h1.y, h1.w, h2.y, h2.w, h3.y, h3.w};
            #pragma unroll
            for (int yl = 0; yl < 4; yl++)
                #pragma unroll
                for (int cl = 0; cl < 8; cl++)
                    acc[yl][cl] += tc[yl] * hr[cl] - ts[yl] * hi[cl];
        }
        const float sc = 1.0f / 131072.0f;
        #pragma unroll
        for (int yl = 0; yl < 4; yl++) {
            int y = yg * 4 + yl;
            float4* d4 = (float4*)(dstb + ((size_t)y * 64 + zc * 8 + dz) * 32 + ch * 16 + cog * 8);
            d4[0] = make_float4(acc[yl][0] * sc, acc[yl][1] * sc, acc[yl][2] * sc, acc[yl][3] * sc);
            d4[1] = make_float4(acc[yl][4] * sc, acc[yl][5] * sc, acc[yl][6] * sc, acc[yl][7] * sc);
        }
    }
}

extern "C" void kernel_launch(void* const* d_in, const int* in_sizes, int n_in,
                              void* d_out, int out_size, void* d_ws, size_t ws_size,
                              hipStream_t stream) {
    const float* x  = (const float*)d_in[0];
    const float* wr = (const float*)d_in[1];
    const float* wi = (const float*)d_in[2];
    float* out = (float*)d_out;
    char*  ws  = (char*)d_ws;
    // T1: 2,097,152 f2 (16.8 MB); XH: 524,288 f2 (4.2 MB); G: 524,288 f2 (4.2 MB)
    float2* T1 = (float2*)ws;
    float2* XH = (float2*)(ws + (size_t)16777216);
    float2* Gb = (float2*)(ws + (size_t)16777216 + 4194304);

    k_dft_z  <<<2560, 256, 0, stream>>>(x, T1, out);   // dft + zero-fill blocks
    k_dft_y  <<< 512, 256, 0, stream>>>(T1, XH);
    k_mid    <<< 256, 256, 0, stream>>>(XH, wr, wi, Gb);
    k_idft_zy<<<1024, 256, 0, stream>>>(Gb, out);
}

// Round 5
// 288.764 us; speedup vs baseline: 2.8338x; 1.0076x over previous
//
#include <hip/hip_runtime.h>
#include <math.h>

#define PI_F 3.14159265358979323846f

// Shapes: B=4, X=Y=Z=64, CIN=COUT=32, modes 16.
// Round-5 structure:
//  K1 z-DFT   : baseline (grid 1024, BW-saturated ~8us).
//  K2 y-DFT   : baseline (grid 512).
//  K3 fused   : 512 threads (2 waves/SIMD; weights still read once as full
//               64B lines) + 1536 zero-fill blocks appended to the grid so
//               the 100MB out[x>=16] fill streams on K3's idle write BW,
//               concurrent with the 256 compute blocks.
//  K4 fused   : active x<16 only, co-half split (grid 1024, ~28KB LDS).

// ---------------- K1: forward z-DFT (baseline) -----------------------------
// grid 1024 = (b4, x16, yg8, ih2); block 256; tile 2kz x 4i per thread.
__global__ __launch_bounds__(256) void k_dft_z(const float* __restrict__ x,
                                               float2* __restrict__ T1) {
    int bid = blockIdx.x;
    int ih = bid & 1, yg = (bid >> 1) & 7, xx = (bid >> 4) & 15, b = bid >> 8;
    __shared__ float  sx[8192];      // [y8][z64][i16] 32KB
    __shared__ float2 twt[1024];     // [z][kz16] 8KB
    float4* sx4 = (float4*)sx;
    const float4* src4 = (const float4*)(x + (size_t)((b * 64 + xx) * 64 + yg * 8) * 2048) + ih * 4;
    #pragma unroll
    for (int t = threadIdx.x; t < 2048; t += 256) {
        int i4 = t & 3, z = (t >> 2) & 63, y = t >> 8;
        sx4[(y * 64 + z) * 4 + i4] = src4[(size_t)y * 512 + z * 8 + i4];
    }
    const float cn = -2.0f * PI_F / 64.0f;
    for (int t = threadIdx.x; t < 1024; t += 256) {
        int z = t >> 4, kz = t & 15;
        float s, c; sincosf(cn * (float)((z * kz) & 63), &s, &c);
        twt[t] = make_float2(c, s);
    }
    __syncthreads();
    int ig = threadIdx.x & 3, kz2 = (threadIdx.x >> 2) & 7, y8 = threadIdx.x >> 5;
    float ar0[4], ai0[4], ar1[4], ai1[4];
    #pragma unroll
    for (int j = 0; j < 4; j++) { ar0[j] = ai0[j] = ar1[j] = ai1[j] = 0.f; }
    const float4* twv = (const float4*)twt;   // [z][8]: (c0,s0,c1,s1) per kz-pair
    #pragma unroll 8
    for (int z = 0; z < 64; z++) {
        float4 va = sx4[(y8 * 64 + z) * 4 + ig];
        float4 tp = twv[z * 8 + kz2];
        float v[4] = {va.x, va.y, va.z, va.w};
        #pragma unroll
        for (int j = 0; j < 4; j++) {
            ar0[j] = fmaf(v[j], tp.x, ar0[j]);
            ai0[j] = fmaf(v[j], tp.y, ai0[j]);
            ar1[j] = fmaf(v[j], tp.z, ar1[j]);
            ai1[j] = fmaf(v[j], tp.w, ai1[j]);
        }
    }
    int y = yg * 8 + y8, kz0 = kz2 * 2, i0 = ih * 16 + ig * 4;
    float2* dst = T1 + (size_t)((b * 16 + xx) * 64 + y) * 512;
    float4* d0 = (float4*)(dst + kz0 * 32 + i0);
    d0[0] = make_float4(ar0[0], ai0[0], ar0[1], ai0[1]);
    d0[1] = make_float4(ar0[2], ai0[2], ar0[3], ai0[3]);
    float4* d1 = (float4*)(dst + (kz0 + 1) * 32 + i0);
    d1[0] = make_float4(ar1[0], ai1[0], ar1[1], ai1[1]);
    d1[1] = make_float4(ar1[2], ai1[2], ar1[3], ai1[3]);
}

// ---------------- K2: forward y-DFT (baseline) -----------------------------
// grid 512 = (b4, x16, kzg4, ih2); block 256; tile 2ky x 2i per thread.
__global__ __launch_bounds__(256) void k_dft_y(const float2* __restrict__ T1,
                                               float2* __restrict__ XH) {
    int bid = blockIdx.x;
    int ih = bid & 1, kzg = (bid >> 1) & 3, xx = (bid >> 3) & 15, b = bid >> 7;
    __shared__ float4 sT4[2304];     // [kz4][y(stride 9)][i4 8] ~37KB
    __shared__ float2 twt[1024];     // [y][ky16] 8KB
    const float4* Tg4 = (const float4*)T1;
    size_t gbase = (size_t)(b * 16 + xx) * 64 * 256;
    #pragma unroll
    for (int t = threadIdx.x; t < 2048; t += 256) {
        int i4 = t & 7, kz4 = (t >> 3) & 3, y = t >> 5;
        sT4[kz4 * 576 + y * 9 + i4] =
            Tg4[gbase + (size_t)y * 256 + (kzg * 4 + kz4) * 16 + ih * 8 + i4];
    }
    const float cn = -2.0f * PI_F / 64.0f;
    for (int t = threadIdx.x; t < 1024; t += 256) {
        int y = t >> 4, ky = t & 15;
        float s, c; sincosf(cn * (float)((y * ky) & 63), &s, &c);
        twt[t] = make_float2(c, s);
    }
    __syncthreads();
    int ig = threadIdx.x & 7, ky2 = (threadIdx.x >> 3) & 7, kz4 = threadIdx.x >> 6;
    float ar[2][2], ai[2][2];
    #pragma unroll
    for (int h = 0; h < 2; h++) { ar[h][0] = ar[h][1] = ai[h][0] = ai[h][1] = 0.f; }
    const float4* twv = (const float4*)twt;
    #pragma unroll 8
    for (int y = 0; y < 64; y++) {
        float4 a  = sT4[kz4 * 576 + y * 9 + ig];   // (xr0,xi0,xr1,xi1)
        float4 tp = twv[y * 8 + ky2];              // (c0,s0,c1,s1)
        float xr[2] = {a.x, a.z}, xi[2] = {a.y, a.w};
        #pragma unroll
        for (int j = 0; j < 2; j++) {
            ar[0][j] += xr[j] * tp.x - xi[j] * tp.y;
            ai[0][j] += xr[j] * tp.y + xi[j] * tp.x;
            ar[1][j] += xr[j] * tp.z - xi[j] * tp.w;
            ai[1][j] += xr[j] * tp.w + xi[j] * tp.z;
        }
    }
    int kz = kzg * 4 + kz4;
    #pragma unroll
    for (int h = 0; h < 2; h++) {
        int ky = ky2 * 2 + h;
        float2* dp = XH + (((size_t)(b * 16 + xx) * 16 + ky) * 16 + kz) * 32 + ih * 16 + ig * 2;
        *(float4*)dp = make_float4(ar[h][0], ai[h][0], ar[h][1], ai[h][1]);
    }
}

// ---------------- K3: fused i-DFT + w-mul + o-IDFT + zero-fill -------------
// grid 1792 = 256 compute (x16, ky16) + 1536 fill; block 512.
// Compute blocks dispatched first; fill blocks stream out[x>=16] zeros on
// the spare write BW while compute blocks are latency-bound.
__global__ __launch_bounds__(512) void k_mid(const float2* __restrict__ XH,
                                             const float* __restrict__ wr,
                                             const float* __restrict__ wi,
                                             float2* __restrict__ G,
                                             float* __restrict__ out) {
    int bid = blockIdx.x;
    if (bid >= 256) {
        // zero-fill out[b][16..63][*][*][*]: 1536 blocks x 64KB contiguous.
        int f = bid - 256;
        int b = f / 384, rem = f - b * 384;
        float4* d4 = (float4*)(out + (size_t)(b * 64 + 16) * 131072) + (size_t)rem * 4096;
        #pragma unroll
        for (int r = 0; r < 8; ++r)
            d4[r * 512 + threadIdx.x] = make_float4(0.f, 0.f, 0.f, 0.f);
        return;
    }
    int ky = bid & 15, xx = bid >> 4;
    __shared__ float2 sA[4 * 528];   // [b][kz(stride33)][i] ; reused as F[b][kz][o]
    __shared__ float2 sB[4 * 576];   // [b][ki(stride18)][kz]
    __shared__ float2 twt[1024];     // [m][k] = exp(-2pi i mk/32)
    for (int t = threadIdx.x; t < 2048; t += 512) {
        int b = t >> 9, kz = (t >> 5) & 15, i = t & 31;
        sA[b * 528 + kz * 33 + i] =
            XH[(((size_t)(b * 16 + xx) * 16 + ky) * 16 + kz) * 32 + i];
    }
    const float cn32 = -2.0f * PI_F / 32.0f;
    for (int t = threadIdx.x; t < 1024; t += 512) {
        int m = t >> 5, k = t & 31;
        float s, c; sincosf(cn32 * (float)((m * k) & 31), &s, &c);
        twt[t] = make_float2(c, s);
    }
    __syncthreads();
    const float4* twv = (const float4*)twt;
    // phase 1: X2[b][ki][kz] = sum_i tw[ki,i] * XH[b][kz][i]  (4ki x 1kz per thread)
    {
        int kz = threadIdx.x & 15, kig = (threadIdx.x >> 4) & 7, b = threadIdx.x >> 7;
        float xr[4], xi[4];
        #pragma unroll
        for (int j = 0; j < 4; j++) { xr[j] = xi[j] = 0.f; }
        #pragma unroll 8
        for (int i = 0; i < 32; i++) {
            float2 a   = sA[b * 528 + kz * 33 + i];
            float4 tp0 = twv[i * 16 + kig * 2];       // ki = kig*4+0,1
            float4 tp1 = twv[i * 16 + kig * 2 + 1];   // ki = kig*4+2,3
            xr[0] += a.x * tp0.x - a.y * tp0.y;  xi[0] += a.x * tp0.y + a.y * tp0.x;
            xr[1] += a.x * tp0.z - a.y * tp0.w;  xi[1] += a.x * tp0.w + a.y * tp0.z;
            xr[2] += a.x * tp1.x - a.y * tp1.y;  xi[2] += a.x * tp1.y + a.y * tp1.x;
            xr[3] += a.x * tp1.z - a.y * tp1.w;  xi[3] += a.x * tp1.w + a.y * tp1.z;
        }
        #pragma unroll
        for (int j = 0; j < 4; j++)
            sB[b * 576 + (kig * 4 + j) * 18 + kz] = make_float2(xr[j], xi[j]);
    }
    __syncthreads();
    // phase 2: F[b][kz][o] = sum_ki X2[b][ki][kz] * w[ki,o]  (1o x 4kz per thread)
    // Wave = 4kzg x 16o: per (ki,o) the 4 kzg lanes read one contiguous 64B
    // line; each line is read by exactly one block globally (weights once).
    {
        int kzg = threadIdx.x & 3, o = (threadIdx.x >> 2) & 31, b = threadIdx.x >> 7;
        int wbase = xx * 256 + ky * 16 + kzg * 4;
        float Fr[4], Fi[4];
        #pragma unroll
        for (int q = 0; q < 4; q++) { Fr[q] = Fi[q] = 0.f; }
        const float4* sB4 = (const float4*)sB;     // f4 stride 9 per ki
        #pragma unroll 4
        for (int ki = 0; ki < 32; ki++) {
            float4 a01 = sB4[b * 288 + ki * 9 + kzg * 2];
            float4 a23 = sB4[b * 288 + ki * 9 + kzg * 2 + 1];
            float4 w4r = *(const float4*)(wr + (size_t)(ki * 32 + o) * 4096 + wbase);
            float4 w4i = *(const float4*)(wi + (size_t)(ki * 32 + o) * 4096 + wbase);
            float xr[4]  = {a01.x, a01.z, a23.x, a23.z};
            float xi[4]  = {a01.y, a01.w, a23.y, a23.w};
            float wrv[4] = {w4r.x, w4r.y, w4r.z, w4r.w};
            float wiv[4] = {w4i.x, w4i.y, w4i.z, w4i.w};
            #pragma unroll
            for (int q = 0; q < 4; q++) {
                Fr[q] += xr[q] * wrv[q] - xi[q] * wiv[q];
                Fi[q] += xr[q] * wiv[q] + xi[q] * wrv[q];
            }
        }
        #pragma unroll
        for (int q = 0; q < 4; q++) {
            int kz = kzg * 4 + q;
            sA[b * 528 + kz * 33 + o] = make_float2(Fr[q], Fi[q]);
        }
    }
    __syncthreads();
    // phase 3: G[b][kz][co] = sum_o conj(tw[co,o]) * F[b][kz][o] (4co x 1kz per thread)
    {
        int kz = threadIdx.x & 15, cog = (threadIdx.x >> 4) & 7, b = threadIdx.x >> 7;
        float gr[4], gi[4];
        #pragma unroll
        for (int j = 0; j < 4; j++) { gr[j] = gi[j] = 0.f; }
        #pragma unroll 8
        for (int o = 0; o < 32; o++) {
            float2 f   = sA[b * 528 + kz * 33 + o];
            float4 tp0 = twv[o * 16 + cog * 2];       // co = cog*4+0,1
            float4 tp1 = twv[o * 16 + cog * 2 + 1];   // co = cog*4+2,3
            gr[0] += f.x * tp0.x + f.y * tp0.y;  gi[0] += f.y * tp0.x - f.x * tp0.y;
            gr[1] += f.x * tp0.z + f.y * tp0.w;  gi[1] += f.y * tp0.z - f.x * tp0.w;
            gr[2] += f.x * tp1.x + f.y * tp1.y;  gi[2] += f.y * tp1.x - f.x * tp1.y;
            gr[3] += f.x * tp1.z + f.y * tp1.w;  gi[3] += f.y * tp1.z - f.x * tp1.w;
        }
        float2* dp = G + (((size_t)(b * 16 + xx) * 16 + ky) * 16 + kz) * 32 + cog * 4;
        ((float4*)dp)[0] = make_float4(gr[0], gi[0], gr[1], gi[1]);
        ((float4*)dp)[1] = make_float4(gr[2], gi[2], gr[3], gi[3]);
    }
}

// ---------------- K4: fused z-IDFT + y-IDFT + Re + scale (active x only) ---
// grid 1024 = (b4, x16, zc8, ch2); block 256. Zero region handled in K3.
// LDS ~27.5KB -> 4-5 blk/CU co-resident.
__global__ __launch_bounds__(256) void k_idft_zy(const float2* __restrict__ G,
                                                 float* __restrict__ out) {
    int bid = blockIdx.x;
    int ch = bid & 1, zc = (bid >> 1) & 7, xx = (bid >> 4) & 15, b = bid >> 8;
    float* dstb = out + (size_t)(b * 64 + xx) * 131072;   // [y][z][co]
    __shared__ float2 sH[128 * 18];  // row R=ky*8+dz, stride 18, [co16]  ~18.4KB
    __shared__ float2 twy[1024];     // [ky][y] 8KB
    __shared__ float2 twz[8 * 17];   // [dz][kz] padded
    const float cp = 2.0f * PI_F / 64.0f;
    for (int t = threadIdx.x; t < 1024; t += 256) {
        int ky = t >> 6, y = t & 63;
        float s, c; sincosf(cp * (float)((ky * y) & 63), &s, &c);
        twy[t] = make_float2(c, s);
    }
    if (threadIdx.x < 128) {
        int dz = threadIdx.x >> 4, kz = threadIdx.x & 15;
        int z = zc * 8 + dz;
        float s, c; sincosf(cp * (float)((kz * z) & 63), &s, &c);
        twz[dz * 17 + kz] = make_float2(c, s);
    }
    __syncthreads();
    // phase Z: H[ky][dz][co16] = sum_kz twz[dz,kz] * G[ky][kz][co-half]
    {
        int coq = threadIdx.x & 1, dz = (threadIdx.x >> 1) & 7, ky = threadIdx.x >> 4;
        const float2* Gb = G + ((size_t)(b * 16 + xx) * 16 + ky) * 512 + ch * 16 + coq * 8;
        float Hr[8], Hi[8];
        #pragma unroll
        for (int j = 0; j < 8; j++) { Hr[j] = Hi[j] = 0.f; }
        #pragma unroll 4
        for (int kz = 0; kz < 16; kz++) {
            float2 tz = twz[dz * 17 + kz];
            #pragma unroll
            for (int k = 0; k < 4; k++) {
                float4 g = *(const float4*)(Gb + kz * 32 + k * 2);
                Hr[2 * k]     += g.x * tz.x - g.y * tz.y;
                Hi[2 * k]     += g.x * tz.y + g.y * tz.x;
                Hr[2 * k + 1] += g.z * tz.x - g.w * tz.y;
                Hi[2 * k + 1] += g.z * tz.y + g.w * tz.x;
            }
        }
        float2* hp = sH + (ky * 8 + dz) * 18 + coq * 8;
        #pragma unroll
        for (int k = 0; k < 4; k++)
            *(float4*)(hp + k * 2) = make_float4(Hr[2 * k], Hi[2 * k], Hr[2 * k + 1], Hi[2 * k + 1]);
    }
    __syncthreads();
    // phase Y: out[y][dz][co16] = Re sum_ky twy[y,ky] * H[ky][dz][co16]
    {
        int cog = threadIdx.x & 1, dz = (threadIdx.x >> 1) & 7, yg = threadIdx.x >> 4;
        float acc[4][8];
        #pragma unroll
        for (int yl = 0; yl < 4; yl++)
            #pragma unroll
            for (int cl = 0; cl < 8; cl++) acc[yl][cl] = 0.f;
        const float4* twy4 = (const float4*)twy;
        const float4* sH4 = (const float4*)sH;    // f4 stride 9 per row
        for (int ky = 0; ky < 16; ky++) {
            float4 t0 = twy4[ky * 32 + yg * 2 + 0];
            float4 t1 = twy4[ky * 32 + yg * 2 + 1];
            float4 h0 = sH4[(ky * 8 + dz) * 9 + cog * 4 + 0];
            float4 h1 = sH4[(ky * 8 + dz) * 9 + cog * 4 + 1];
            float4 h2 = sH4[(ky * 8 + dz) * 9 + cog * 4 + 2];
            float4 h3 = sH4[(ky * 8 + dz) * 9 + cog * 4 + 3];
            float tc[4] = {t0.x, t0.z, t1.x, t1.z};
            float ts[4] = {t0.y, t0.w, t1.y, t1.w};
            float hr[8] = {h0.x, h0.z, h1.x, h1.z, h2.x, h2.z, h3.x, h3.z};
            float hi[8] = {h0.y, h0.w, h1.y, h1.w, h2.y, h2.w, h3.y, h3.w};
            #pragma unroll
            for (int yl = 0; yl < 4; yl++)
                #pragma unroll
                for (int cl = 0; cl < 8; cl++)
                    acc[yl][cl] += tc[yl] * hr[cl] - ts[yl] * hi[cl];
        }
        const float sc = 1.0f / 131072.0f;
        #pragma unroll
        for (int yl = 0; yl < 4; yl++) {
            int y = yg * 4 + yl;
            float4* d4 = (float4*)(dstb + ((size_t)y * 64 + zc * 8 + dz) * 32 + ch * 16 + cog * 8);
            d4[0] = make_float4(acc[yl][0] * sc, acc[yl][1] * sc, acc[yl][2] * sc, acc[yl][3] * sc);
            d4[1] = make_float4(acc[yl][4] * sc, acc[yl][5] * sc, acc[yl][6] * sc, acc[yl][7] * sc);
        }
    }
}

extern "C" void kernel_launch(void* const* d_in, const int* in_sizes, int n_in,
                              void* d_out, int out_size, void* d_ws, size_t ws_size,
                              hipStream_t stream) {
    const float* x  = (const float*)d_in[0];
    const float* wr = (const float*)d_in[1];
    const float* wi = (const float*)d_in[2];
    float* out = (float*)d_out;
    char*  ws  = (char*)d_ws;
    // T1: 2,097,152 f2 (16.8 MB); XH: 524,288 f2 (4.2 MB); G: 524,288 f2 (4.2 MB)
    float2* T1 = (float2*)ws;
    float2* XH = (float2*)(ws + (size_t)16777216);
    float2* Gb = (float2*)(ws + (size_t)16777216 + 4194304);

    k_dft_z  <<<1024, 256, 0, stream>>>(x, T1);
    k_dft_y  <<< 512, 256, 0, stream>>>(T1, XH);
    k_mid    <<<1792, 512, 0, stream>>>(XH, wr, wi, Gb, out);  // compute + fill
    k_idft_zy<<<1024, 256, 0, stream>>>(Gb, out);
}